// Round 2
// baseline (148.567 us; speedup 1.0000x reference)
//
#include <hip/hip_runtime.h>
#include <hip/hip_fp16.h>

// out[b,o] = sum_k x[b, conn[o,k]] * w[o,k]
// B=1024, In=8192, O=8192, K=32.
//
// R1: latency-bound fix. Grid 512 (batch-tile x output-half) so 2 blocks/CU
// are co-resident (2 x 64KiB LDS = 128 <= 160 KiB) -> 4 waves/SIMD instead
// of 2. unroll-2 on the output loop doubles in-flight loads per wave.
// Data layout unchanged: x[4 rows] transposed in LDS as packed f16x4,
// one ds_read_b64 serves 4 batch rows per gather index.

constexpr int IN_F   = 8192;
constexpr int OUT_F  = 8192;
constexpr int KPER   = 32;
constexpr int BATCH  = 1024;
constexpr int ROWS   = 4;     // batch rows per block
constexpr int THREADS = 512;  // 8 waves
constexpr int OHALF  = OUT_F / 2;  // outputs per block

__global__ __launch_bounds__(THREADS, 4)
void psl_kernel(const float* __restrict__ x,
                const int*   __restrict__ conn,
                const float* __restrict__ w,
                float*       __restrict__ out) {
    __shared__ uint2 lds_x[IN_F];  // 64 KiB: [col] -> 4 batch rows as f16

    const int tid = threadIdx.x;
    const int bt  = blockIdx.x >> 1;      // batch tile
    const int oh  = blockIdx.x & 1;       // output half
    const long b0 = (long)bt * ROWS;

    const float* xr0 = x + (b0 + 0) * IN_F;
    const float* xr1 = x + (b0 + 1) * IN_F;
    const float* xr2 = x + (b0 + 2) * IN_F;
    const float* xr3 = x + (b0 + 3) * IN_F;

    // Stage: coalesced dword reads per row, pack 4 rows -> 8 B, one
    // ds_write_b64 per column (lane-stride 8 B: conflict-free).
    for (int c = tid; c < IN_F; c += THREADS) {
        __half2 h01 = __floats2half2_rn(xr0[c], xr1[c]);
        __half2 h23 = __floats2half2_rn(xr2[c], xr3[c]);
        uint2 pk;
        pk.x = *reinterpret_cast<unsigned*>(&h01);
        pk.y = *reinterpret_cast<unsigned*>(&h23);
        lds_x[c] = pk;
    }
    __syncthreads();

    float* or0 = out + (b0 + 0) * OUT_F;
    float* or1 = out + (b0 + 1) * OUT_F;
    float* or2 = out + (b0 + 2) * OUT_F;
    float* or3 = out + (b0 + 3) * OUT_F;

    const int obase = oh * OHALF;

#pragma unroll 2
    for (int j = 0; j < OHALF / THREADS; ++j) {
        const int o = obase + j * THREADS + tid;
        const int4*   c4 = reinterpret_cast<const int4*>(conn + (size_t)o * KPER);
        const float4* w4 = reinterpret_cast<const float4*>(w + (size_t)o * KPER);

        float a0 = 0.f, a1 = 0.f, a2 = 0.f, a3 = 0.f;

#define GACC(IDX, WT)                                              \
        {                                                          \
            uint2 v = lds_x[(IDX)];                                \
            __half2 h01 = *reinterpret_cast<__half2*>(&v.x);       \
            __half2 h23 = *reinterpret_cast<__half2*>(&v.y);       \
            float2 f01 = __half22float2(h01);                      \
            float2 f23 = __half22float2(h23);                      \
            a0 = fmaf(f01.x, (WT), a0);                            \
            a1 = fmaf(f01.y, (WT), a1);                            \
            a2 = fmaf(f23.x, (WT), a2);                            \
            a3 = fmaf(f23.y, (WT), a3);                            \
        }

#pragma unroll
        for (int jj = 0; jj < KPER / 4; ++jj) {
            const int4   ci = c4[jj];
            const float4 wj = w4[jj];
            GACC(ci.x, wj.x);
            GACC(ci.y, wj.y);
            GACC(ci.z, wj.z);
            GACC(ci.w, wj.w);
        }
#undef GACC

        or0[o] = a0;
        or1[o] = a1;
        or2[o] = a2;
        or3[o] = a3;
    }
}

extern "C" void kernel_launch(void* const* d_in, const int* in_sizes, int n_in,
                              void* d_out, int out_size, void* d_ws, size_t ws_size,
                              hipStream_t stream) {
    const float* x    = (const float*)d_in[0];
    const int*   conn = (const int*)d_in[1];
    const float* w    = (const float*)d_in[2];
    float*       out  = (float*)d_out;

    dim3 grid((BATCH / ROWS) * 2);  // 512 blocks -> 2 per CU
    psl_kernel<<<grid, THREADS, 0, stream>>>(x, conn, w, out);
}

// Round 3
// 117.059 us; speedup vs baseline: 1.2692x; 1.2692x over previous
//
#include <hip/hip_runtime.h>
#include <hip/hip_fp16.h>

// out[b,o] = sum_k x[b, conn[o,k]] * w[o,k]
// B=1024, In=8192, O=8192, K=32.
//
// R2: kill VMEM transaction amplification. R1 read conn/w rows per-lane
// (adjacent lanes 128 B apart -> 64 cachelines per dwordx4 instr; ~131k
// line-transactions/CU was the hidden bottleneck). Now a pre-kernel
// repacks conn+w into transposed interleaved pk[k2][o] = {i0,w0,i1,w1}
// so main-loop loads are lane-contiguous (16 lines/instr, the minimum).
// x staging unchanged: 4 batch rows transposed in LDS as packed f16x4,
// one ds_read_b64 serves 4 batch rows per gather index.

constexpr int IN_F    = 8192;
constexpr int OUT_F   = 8192;
constexpr int KPER    = 32;
constexpr int BATCH   = 1024;
constexpr int ROWS    = 4;        // batch rows per block
constexpr int THREADS = 512;      // 8 waves
constexpr int OHALF   = OUT_F / 2;
constexpr size_t PK_BYTES = (size_t)OUT_F * (KPER / 2) * 16;  // 2 MiB

// ---- repack: pk[k2][o] = {conn[o][2k2], w[o][2k2], conn[o][2k2+1], w[o][2k2+1]}
__global__ __launch_bounds__(256)
void psl_repack(const int* __restrict__ conn, const float* __restrict__ w,
                uint4* __restrict__ pk) {
    const int t  = blockIdx.x * 256 + threadIdx.x;   // OUT_F*16 threads
    const int o  = t >> 4;
    const int k2 = t & 15;
    const int base = o * KPER + k2 * 2;
    uint4 v;
    v.x = (unsigned)conn[base];
    v.y = __float_as_uint(w[base]);
    v.z = (unsigned)conn[base + 1];
    v.w = __float_as_uint(w[base + 1]);
    pk[(size_t)k2 * OUT_F + o] = v;   // scattered writes, tiny total (4 MB)
}

// ---- main kernel (repacked path)
__global__ __launch_bounds__(THREADS, 4)
void psl_main(const float* __restrict__ x, const uint4* __restrict__ pk,
              float* __restrict__ out) {
    __shared__ uint2 lds_x[IN_F];  // 64 KiB: [col] -> 4 batch rows as f16

    const int tid = threadIdx.x;
    const int bt  = blockIdx.x >> 1;      // batch tile
    const int oh  = blockIdx.x & 1;       // output half
    const long b0 = (long)bt * ROWS;

    const float* xr0 = x + (b0 + 0) * IN_F;
    const float* xr1 = x + (b0 + 1) * IN_F;
    const float* xr2 = x + (b0 + 2) * IN_F;
    const float* xr3 = x + (b0 + 3) * IN_F;

    for (int c = tid; c < IN_F; c += THREADS) {
        __half2 h01 = __floats2half2_rn(xr0[c], xr1[c]);
        __half2 h23 = __floats2half2_rn(xr2[c], xr3[c]);
        uint2 pkx;
        pkx.x = *reinterpret_cast<unsigned*>(&h01);
        pkx.y = *reinterpret_cast<unsigned*>(&h23);
        lds_x[c] = pkx;
    }
    __syncthreads();

    float* or0 = out + (b0 + 0) * OUT_F;
    float* or1 = out + (b0 + 1) * OUT_F;
    float* or2 = out + (b0 + 2) * OUT_F;
    float* or3 = out + (b0 + 3) * OUT_F;

    const int obase = oh * OHALF;

    for (int j = 0; j < OHALF / THREADS; ++j) {
        const int o = obase + j * THREADS + tid;
        float a0 = 0.f, a1 = 0.f, a2 = 0.f, a3 = 0.f;

#pragma unroll
        for (int k2 = 0; k2 < KPER / 2; ++k2) {
            const uint4 v = pk[(size_t)k2 * OUT_F + o];  // lane-contiguous
            const uint2 g0 = lds_x[v.x];
            const uint2 g1 = lds_x[v.z];
            const float w0 = __uint_as_float(v.y);
            const float w1 = __uint_as_float(v.w);

            __half2 h01 = *reinterpret_cast<const __half2*>(&g0.x);
            __half2 h23 = *reinterpret_cast<const __half2*>(&g0.y);
            float2 f01 = __half22float2(h01);
            float2 f23 = __half22float2(h23);
            a0 = fmaf(f01.x, w0, a0);
            a1 = fmaf(f01.y, w0, a1);
            a2 = fmaf(f23.x, w0, a2);
            a3 = fmaf(f23.y, w0, a3);

            h01 = *reinterpret_cast<const __half2*>(&g1.x);
            h23 = *reinterpret_cast<const __half2*>(&g1.y);
            f01 = __half22float2(h01);
            f23 = __half22float2(h23);
            a0 = fmaf(f01.x, w1, a0);
            a1 = fmaf(f01.y, w1, a1);
            a2 = fmaf(f23.x, w1, a2);
            a3 = fmaf(f23.y, w1, a3);
        }

        or0[o] = a0;
        or1[o] = a1;
        or2[o] = a2;
        or3[o] = a3;
    }
}

// ---- fallback (R1 path) in case ws_size < 2 MiB
__global__ __launch_bounds__(THREADS, 4)
void psl_fallback(const float* __restrict__ x, const int* __restrict__ conn,
                  const float* __restrict__ w, float* __restrict__ out) {
    __shared__ uint2 lds_x[IN_F];
    const int tid = threadIdx.x;
    const int bt  = blockIdx.x >> 1;
    const int oh  = blockIdx.x & 1;
    const long b0 = (long)bt * ROWS;
    const float* xr0 = x + (b0 + 0) * IN_F;
    const float* xr1 = x + (b0 + 1) * IN_F;
    const float* xr2 = x + (b0 + 2) * IN_F;
    const float* xr3 = x + (b0 + 3) * IN_F;
    for (int c = tid; c < IN_F; c += THREADS) {
        __half2 h01 = __floats2half2_rn(xr0[c], xr1[c]);
        __half2 h23 = __floats2half2_rn(xr2[c], xr3[c]);
        uint2 pkx;
        pkx.x = *reinterpret_cast<unsigned*>(&h01);
        pkx.y = *reinterpret_cast<unsigned*>(&h23);
        lds_x[c] = pkx;
    }
    __syncthreads();
    float* or0 = out + (b0 + 0) * OUT_F;
    float* or1 = out + (b0 + 1) * OUT_F;
    float* or2 = out + (b0 + 2) * OUT_F;
    float* or3 = out + (b0 + 3) * OUT_F;
    const int obase = oh * OHALF;
    for (int j = 0; j < OHALF / THREADS; ++j) {
        const int o = obase + j * THREADS + tid;
        const int4*   c4 = reinterpret_cast<const int4*>(conn + (size_t)o * KPER);
        const float4* w4 = reinterpret_cast<const float4*>(w + (size_t)o * KPER);
        float a0 = 0.f, a1 = 0.f, a2 = 0.f, a3 = 0.f;
#define GACC(IDX, WT)                                              \
        {                                                          \
            uint2 v = lds_x[(IDX)];                                \
            __half2 h01 = *reinterpret_cast<__half2*>(&v.x);       \
            __half2 h23 = *reinterpret_cast<__half2*>(&v.y);       \
            float2 f01 = __half22float2(h01);                      \
            float2 f23 = __half22float2(h23);                      \
            a0 = fmaf(f01.x, (WT), a0);                            \
            a1 = fmaf(f01.y, (WT), a1);                            \
            a2 = fmaf(f23.x, (WT), a2);                            \
            a3 = fmaf(f23.y, (WT), a3);                            \
        }
#pragma unroll
        for (int jj = 0; jj < KPER / 4; ++jj) {
            const int4   ci = c4[jj];
            const float4 wj = w4[jj];
            GACC(ci.x, wj.x);
            GACC(ci.y, wj.y);
            GACC(ci.z, wj.z);
            GACC(ci.w, wj.w);
        }
#undef GACC
        or0[o] = a0;
        or1[o] = a1;
        or2[o] = a2;
        or3[o] = a3;
    }
}

extern "C" void kernel_launch(void* const* d_in, const int* in_sizes, int n_in,
                              void* d_out, int out_size, void* d_ws, size_t ws_size,
                              hipStream_t stream) {
    const float* x    = (const float*)d_in[0];
    const int*   conn = (const int*)d_in[1];
    const float* w    = (const float*)d_in[2];
    float*       out  = (float*)d_out;

    if (ws_size >= PK_BYTES) {
        uint4* pk = (uint4*)d_ws;
        psl_repack<<<dim3(OUT_F * (KPER / 2) / 256), 256, 0, stream>>>(conn, w, pk);
        psl_main<<<dim3((BATCH / ROWS) * 2), THREADS, 0, stream>>>(x, pk, out);
    } else {
        psl_fallback<<<dim3((BATCH / ROWS) * 2), THREADS, 0, stream>>>(x, conn, w, out);
    }
}

// Round 4
// 104.221 us; speedup vs baseline: 1.4255x; 1.1232x over previous
//
#include <hip/hip_runtime.h>
#include <hip/hip_fp16.h>

// out[b,o] = sum_k x[b, conn[o,k]] * w[o,k]
// B=1024, In=8192, O=8192, K=32.
//
// R3: (a) pk compacted to 8 B per (idx,w) pair: u16 pre-scaled LDS byte
// offset + f16 weight -> half the pk VMEM lines of R2. (b) inner loop uses
// v_perm_b32 + v_dot2_f32_f16 (2 f16 MACs -> f32 acc per instr) instead of
// cvt+fma chains -> ~40% fewer VALU ops. (c) 1024-thread blocks, 2/CU
// co-resident -> 8 waves/SIMD (was 4). x staging unchanged: 4 batch rows
// transposed in LDS as packed f16x4; one ds_read_b64 serves 4 rows/gather.

typedef _Float16 half2_t __attribute__((ext_vector_type(2)));

constexpr int IN_F    = 8192;
constexpr int OUT_F   = 8192;
constexpr int KPER    = 32;
constexpr int BATCH   = 1024;
constexpr int ROWS    = 4;         // batch rows per block
constexpr int THREADS = 1024;      // 16 waves
constexpr int OHALF   = OUT_F / 2; // outputs per block
constexpr size_t PK_BYTES = (size_t)OUT_F * (KPER / 4) * 16;  // 1 MiB

// pk[j][o] (j = k/4) : uint4 {off0|off1<<16, half2(w0,w1), off2|off3<<16,
// half2(w2,w3)} where offN = conn[o][4j+N] * 8 (LDS byte offset).
__global__ __launch_bounds__(256)
void psl_repack(const int* __restrict__ conn, const float* __restrict__ w,
                uint4* __restrict__ pk) {
    const int t = blockIdx.x * 256 + threadIdx.x;  // OUT_F * 8 threads
    const int j = t >> 13;          // 0..7
    const int o = t & (OUT_F - 1);
    const int base = o * KPER + j * 4;
    const int4   ci = *reinterpret_cast<const int4*>(conn + base);
    const float4 wj = *reinterpret_cast<const float4*>(w + base);
    uint4 v;
    v.x = ((unsigned)ci.x << 3) | ((unsigned)ci.y << 19);
    v.z = ((unsigned)ci.z << 3) | ((unsigned)ci.w << 19);
    __half2 w01 = __floats2half2_rn(wj.x, wj.y);
    __half2 w23 = __floats2half2_rn(wj.z, wj.w);
    v.y = *reinterpret_cast<unsigned*>(&w01);
    v.w = *reinterpret_cast<unsigned*>(&w23);
    pk[(size_t)j * OUT_F + o] = v;
}

__device__ __forceinline__ float dot2acc(unsigned hi, unsigned lo,
                                         unsigned sel, unsigned wbits,
                                         float acc) {
    unsigned p = __builtin_amdgcn_perm(hi, lo, sel);
    return __builtin_amdgcn_fdot2(__builtin_bit_cast(half2_t, p),
                                  __builtin_bit_cast(half2_t, wbits),
                                  acc, false);
}

__global__ __launch_bounds__(THREADS, 8)
void psl_main(const float* __restrict__ x, const uint4* __restrict__ pk,
              float* __restrict__ out) {
    __shared__ uint2 lds_x[IN_F];  // 64 KiB: [col] -> 4 batch rows as f16

    const int tid = threadIdx.x;
    const int bt  = blockIdx.x >> 1;      // batch tile
    const int oh  = blockIdx.x & 1;       // output half
    const long b0 = (long)bt * ROWS;

    const float* xr0 = x + (b0 + 0) * IN_F;
    const float* xr1 = x + (b0 + 1) * IN_F;
    const float* xr2 = x + (b0 + 2) * IN_F;
    const float* xr3 = x + (b0 + 3) * IN_F;

    for (int c = tid; c < IN_F; c += THREADS) {
        __half2 h01 = __floats2half2_rn(xr0[c], xr1[c]);
        __half2 h23 = __floats2half2_rn(xr2[c], xr3[c]);
        uint2 pkx;
        pkx.x = *reinterpret_cast<unsigned*>(&h01);
        pkx.y = *reinterpret_cast<unsigned*>(&h23);
        lds_x[c] = pkx;
    }
    __syncthreads();

    float* or0 = out + (b0 + 0) * OUT_F;
    float* or1 = out + (b0 + 1) * OUT_F;
    float* or2 = out + (b0 + 2) * OUT_F;
    float* or3 = out + (b0 + 3) * OUT_F;

    const int obase = oh * OHALF;
    const char* ldsb = reinterpret_cast<const char*>(lds_x);

    for (int jj = 0; jj < OHALF / THREADS; ++jj) {
        const int o = obase + jj * THREADS + tid;
        const uint4* pkrow = pk + o;

        float a0 = 0.f, a1 = 0.f, a2 = 0.f, a3 = 0.f;

#pragma unroll 2
        for (int j = 0; j < KPER / 4; ++j) {
            const uint4 v = pkrow[(size_t)j * OUT_F];  // lane-contiguous 16 B
            const unsigned off0 = v.x & 0xFFFFu, off1 = v.x >> 16;
            const unsigned off2 = v.z & 0xFFFFu, off3 = v.z >> 16;
            const uint2 g0 = *reinterpret_cast<const uint2*>(ldsb + off0);
            const uint2 g1 = *reinterpret_cast<const uint2*>(ldsb + off1);
            const uint2 g2 = *reinterpret_cast<const uint2*>(ldsb + off2);
            const uint2 g3 = *reinterpret_cast<const uint2*>(ldsb + off3);
            // rows 0,1 in .x (half2: lo=row even, hi=row odd); rows 2,3 in .y
            a0 = dot2acc(g1.x, g0.x, 0x05040100u, v.y, a0);
            a1 = dot2acc(g1.x, g0.x, 0x07060302u, v.y, a1);
            a2 = dot2acc(g1.y, g0.y, 0x05040100u, v.y, a2);
            a3 = dot2acc(g1.y, g0.y, 0x07060302u, v.y, a3);
            a0 = dot2acc(g3.x, g2.x, 0x05040100u, v.w, a0);
            a1 = dot2acc(g3.x, g2.x, 0x07060302u, v.w, a1);
            a2 = dot2acc(g3.y, g2.y, 0x05040100u, v.w, a2);
            a3 = dot2acc(g3.y, g2.y, 0x07060302u, v.w, a3);
        }

        or0[o] = a0;
        or1[o] = a1;
        or2[o] = a2;
        or3[o] = a3;
    }
}

// ---- fallback (no-ws path, R1 structure) ----
__global__ __launch_bounds__(512, 4)
void psl_fallback(const float* __restrict__ x, const int* __restrict__ conn,
                  const float* __restrict__ w, float* __restrict__ out) {
    __shared__ uint2 lds_x[IN_F];
    const int tid = threadIdx.x;
    const int bt  = blockIdx.x >> 1;
    const int oh  = blockIdx.x & 1;
    const long b0 = (long)bt * ROWS;
    const float* xr0 = x + (b0 + 0) * IN_F;
    const float* xr1 = x + (b0 + 1) * IN_F;
    const float* xr2 = x + (b0 + 2) * IN_F;
    const float* xr3 = x + (b0 + 3) * IN_F;
    for (int c = tid; c < IN_F; c += 512) {
        __half2 h01 = __floats2half2_rn(xr0[c], xr1[c]);
        __half2 h23 = __floats2half2_rn(xr2[c], xr3[c]);
        uint2 pkx;
        pkx.x = *reinterpret_cast<unsigned*>(&h01);
        pkx.y = *reinterpret_cast<unsigned*>(&h23);
        lds_x[c] = pkx;
    }
    __syncthreads();
    float* or0 = out + (b0 + 0) * OUT_F;
    float* or1 = out + (b0 + 1) * OUT_F;
    float* or2 = out + (b0 + 2) * OUT_F;
    float* or3 = out + (b0 + 3) * OUT_F;
    const int obase = oh * OHALF;
    for (int j = 0; j < OHALF / 512; ++j) {
        const int o = obase + j * 512 + tid;
        const int4*   c4 = reinterpret_cast<const int4*>(conn + (size_t)o * KPER);
        const float4* w4 = reinterpret_cast<const float4*>(w + (size_t)o * KPER);
        float a0 = 0.f, a1 = 0.f, a2 = 0.f, a3 = 0.f;
#define GACC(IDX, WT)                                              \
        {                                                          \
            uint2 v = lds_x[(IDX)];                                \
            __half2 h01 = *reinterpret_cast<__half2*>(&v.x);       \
            __half2 h23 = *reinterpret_cast<__half2*>(&v.y);       \
            float2 f01 = __half22float2(h01);                      \
            float2 f23 = __half22float2(h23);                      \
            a0 = fmaf(f01.x, (WT), a0);                            \
            a1 = fmaf(f01.y, (WT), a1);                            \
            a2 = fmaf(f23.x, (WT), a2);                            \
            a3 = fmaf(f23.y, (WT), a3);                            \
        }
#pragma unroll
        for (int jj = 0; jj < KPER / 4; ++jj) {
            const int4   ci = c4[jj];
            const float4 wj = w4[jj];
            GACC(ci.x, wj.x);
            GACC(ci.y, wj.y);
            GACC(ci.z, wj.z);
            GACC(ci.w, wj.w);
        }
#undef GACC
        or0[o] = a0;
        or1[o] = a1;
        or2[o] = a2;
        or3[o] = a3;
    }
}

extern "C" void kernel_launch(void* const* d_in, const int* in_sizes, int n_in,
                              void* d_out, int out_size, void* d_ws, size_t ws_size,
                              hipStream_t stream) {
    const float* x    = (const float*)d_in[0];
    const int*   conn = (const int*)d_in[1];
    const float* w    = (const float*)d_in[2];
    float*       out  = (float*)d_out;

    if (ws_size >= PK_BYTES) {
        uint4* pk = (uint4*)d_ws;
        psl_repack<<<dim3(OUT_F * (KPER / 4) / 256), 256, 0, stream>>>(conn, w, pk);
        psl_main<<<dim3((BATCH / ROWS) * 2), THREADS, 0, stream>>>(x, pk, out);
    } else {
        psl_fallback<<<dim3((BATCH / ROWS) * 2), 512, 0, stream>>>(x, conn, w, out);
    }
}